// Round 1
// baseline (1148.014 us; speedup 1.0000x reference)
//
#include <hip/hip_runtime.h>

#define F 128
#define TR 128   // GEMM row tile
#define KC 32    // GEMM k chunk
#define LDA 33   // padded LDS leading dim (breaks bank conflicts on x broadcast)

// Detect whether edge_index was stored as int64 (high 32-bit words all zero at
// odd int32 slots) or int32. Values are < 50000 so int64 high words are 0;
// for int32 data, 8 consecutive odd slots being 0 is ~(1/50000)^8.
__global__ void detect_kernel(const int* __restrict__ ei, int* __restrict__ flag)
{
    if (threadIdx.x == 0 && blockIdx.x == 0) {
        int or_hi = ei[1] | ei[3] | ei[5] | ei[7] | ei[9] | ei[11] | ei[13] | ei[15];
        *flag = (or_hi == 0) ? 1 : 0;
    }
}

// One 32-lane group per edge; each thread handles 4 consecutive features.
// agg[dst] += x[src] via hardware fp32 atomics (global_atomic_add_f32).
__global__ __launch_bounds__(256) void scatter_kernel(
    const float* __restrict__ x,
    const int* __restrict__ ei,
    const int* __restrict__ flag_p,
    float* __restrict__ agg,
    int E)
{
    int tid = blockIdx.x * 256 + threadIdx.x;
    int e = tid >> 5;
    if (e >= E) return;
    int c = (tid & 31) << 2;
    int is64 = *flag_p;
    int s, d;
    if (is64) {
        s = ei[2 * (size_t)e];            // low word of int64 src[e]
        d = ei[2 * ((size_t)E + e)];      // low word of int64 dst[e]
    } else {
        s = ei[e];
        d = ei[E + e];
    }
    float4 v = *reinterpret_cast<const float4*>(x + (size_t)s * F + c);
    float* o = agg + (size_t)d * F + c;
    unsafeAtomicAdd(o + 0, v.x);
    unsafeAtomicAdd(o + 1, v.y);
    unsafeAtomicAdd(o + 2, v.z);
    unsafeAtomicAdd(o + 3, v.w);
}

// In-place GEMM: io (=d_out holding agg) -> io = io @ W + bias.
// Safe in-place: each block stages ONLY its own 128 rows into LDS across the
// k-chunk loop, then overwrites those same rows in the epilogue. No block
// reads another block's rows.
__global__ __launch_bounds__(256) void gemm_kernel(
    float* __restrict__ io,
    const float* __restrict__ W,
    const float* __restrict__ bias,
    int N)
{
    __shared__ float sA[TR * LDA];   // 128x32 A chunk, padded stride 33 (16.9 KB)
    __shared__ float sW[KC * F];     // 32x128 W chunk (16 KB)
    const int t = threadIdx.x;
    const int row0 = blockIdx.x * TR;
    const int g = t & 7;             // f-group: covers f = g*16 .. g*16+15
    const int r = t >> 3;            // row-group: rows r*4 .. r*4+3

    float acc[4][16];
    #pragma unroll
    for (int i = 0; i < 4; ++i)
        #pragma unroll
        for (int j = 0; j < 16; ++j) acc[i][j] = 0.0f;

    for (int kc = 0; kc < F; kc += KC) {
        // Stage A chunk: 128 rows x 32 k (scalar loads, coalesced 128B/row).
        #pragma unroll
        for (int u = 0; u < (TR * KC) / 256; ++u) {
            int idx = u * 256 + t;
            int row = idx >> 5;
            int kk = idx & (KC - 1);
            int grow = row0 + row;
            sA[row * LDA + kk] = (grow < N) ? io[(size_t)grow * F + kc + kk] : 0.0f;
        }
        // Stage W chunk: 32 k-rows x 128 f, fully-coalesced float4 loads.
        const float4* Wg = reinterpret_cast<const float4*>(W + (size_t)kc * F);
        float4* sW4 = reinterpret_cast<float4*>(sW);
        #pragma unroll
        for (int u = 0; u < (KC * F / 4) / 256; ++u)
            sW4[u * 256 + t] = Wg[u * 256 + t];
        __syncthreads();

        #pragma unroll 4
        for (int kk = 0; kk < KC; ++kk) {
            const float4 w0 = *reinterpret_cast<const float4*>(&sW[kk * F + g * 16 + 0]);
            const float4 w1 = *reinterpret_cast<const float4*>(&sW[kk * F + g * 16 + 4]);
            const float4 w2 = *reinterpret_cast<const float4*>(&sW[kk * F + g * 16 + 8]);
            const float4 w3 = *reinterpret_cast<const float4*>(&sW[kk * F + g * 16 + 12]);
            #pragma unroll
            for (int i = 0; i < 4; ++i) {
                const float xv = sA[(r * 4 + i) * LDA + kk];
                acc[i][0]  += xv * w0.x;  acc[i][1]  += xv * w0.y;
                acc[i][2]  += xv * w0.z;  acc[i][3]  += xv * w0.w;
                acc[i][4]  += xv * w1.x;  acc[i][5]  += xv * w1.y;
                acc[i][6]  += xv * w1.z;  acc[i][7]  += xv * w1.w;
                acc[i][8]  += xv * w2.x;  acc[i][9]  += xv * w2.y;
                acc[i][10] += xv * w2.z;  acc[i][11] += xv * w2.w;
                acc[i][12] += xv * w3.x;  acc[i][13] += xv * w3.y;
                acc[i][14] += xv * w3.z;  acc[i][15] += xv * w3.w;
            }
        }
        __syncthreads();
    }

    float bv[16];
    #pragma unroll
    for (int j = 0; j < 16; ++j) bv[j] = bias[g * 16 + j];
    #pragma unroll
    for (int i = 0; i < 4; ++i) {
        int row = row0 + r * 4 + i;
        if (row < N) {
            float* o = io + (size_t)row * F + g * 16;
            #pragma unroll
            for (int j4 = 0; j4 < 4; ++j4) {
                float4 v;
                v.x = acc[i][j4 * 4 + 0] + bv[j4 * 4 + 0];
                v.y = acc[i][j4 * 4 + 1] + bv[j4 * 4 + 1];
                v.z = acc[i][j4 * 4 + 2] + bv[j4 * 4 + 2];
                v.w = acc[i][j4 * 4 + 3] + bv[j4 * 4 + 3];
                *reinterpret_cast<float4*>(o + j4 * 4) = v;
            }
        }
    }
}

extern "C" void kernel_launch(void* const* d_in, const int* in_sizes, int n_in,
                              void* d_out, int out_size, void* d_ws, size_t ws_size,
                              hipStream_t stream) {
    const float* x  = (const float*)d_in[0];
    const int*   ei = (const int*)d_in[1];
    const float* W2 = (const float*)d_in[5];
    const float* b2 = (const float*)d_in[6];
    float* out = (float*)d_out;
    int* flag = (int*)d_ws;

    const int N = in_sizes[0] / F;   // 50000
    const int E = in_sizes[2];       // 600000 (edge_weight element count)

    // Zero the aggregation buffer (d_out doubles as agg scratch).
    hipMemsetAsync(out, 0, (size_t)N * F * sizeof(float), stream);

    detect_kernel<<<1, 64, 0, stream>>>(ei, flag);

    int sthreads_total = E * 32;                 // 32 lanes per edge
    int sblocks = (sthreads_total + 255) / 256;
    scatter_kernel<<<sblocks, 256, 0, stream>>>(x, ei, flag, out, E);

    gemm_kernel<<<(N + TR - 1) / TR, 256, 0, stream>>>(out, W2, b2, N);
}

// Round 2
// 253.343 us; speedup vs baseline: 4.5315x; 4.5315x over previous
//
#include <hip/hip_runtime.h>

#define F 128
#define TR 128   // GEMM row tile
#define KC 32    // GEMM k chunk
#define LDA 33   // padded LDS leading dim

// ---------- dtype detect (int64 vs int32 edge_index) ----------
__global__ void detect_kernel(const int* __restrict__ ei, int* __restrict__ flag)
{
    if (threadIdx.x == 0 && blockIdx.x == 0) {
        int or_hi = ei[1] | ei[3] | ei[5] | ei[7] | ei[9] | ei[11] | ei[13] | ei[15];
        *flag = (or_hi == 0) ? 1 : 0;
    }
}

__device__ __forceinline__ void load_edge(const int* ei, int is64, int E, int e,
                                          int& s, int& d)
{
    if (is64) {
        s = ei[2 * (size_t)e];
        d = ei[2 * ((size_t)E + e)];
    } else {
        s = ei[e];
        d = ei[E + e];
    }
}

// ---------- CSR build ----------
__global__ __launch_bounds__(256) void hist_kernel(
    const int* __restrict__ ei, const int* __restrict__ flag_p,
    int* __restrict__ counts, int E)
{
    int e = blockIdx.x * 256 + threadIdx.x;
    if (e >= E) return;
    int is64 = *flag_p;
    int s, d;
    load_edge(ei, is64, E, e, s, d);
    atomicAdd(&counts[d], 1);
}

// Block-level exclusive scan of 256-chunks; blocksums out.
__global__ __launch_bounds__(256) void scan1_kernel(
    const int* __restrict__ counts, int* __restrict__ offsets,
    int* __restrict__ blocksums, int N)
{
    __shared__ int sh[256];
    int t = threadIdx.x;
    int i = blockIdx.x * 256 + t;
    int v = (i < N) ? counts[i] : 0;
    sh[t] = v;
    __syncthreads();
    int inc = v;
    #pragma unroll
    for (int ofs = 1; ofs < 256; ofs <<= 1) {
        int add = (t >= ofs) ? sh[t - ofs] : 0;
        __syncthreads();
        inc += add;
        sh[t] = inc;
        __syncthreads();
    }
    if (i < N) offsets[i] = inc - v;          // exclusive within block
    if (t == 255) blocksums[blockIdx.x] = inc; // block total
}

// Single block: exclusive scan of blocksums (nblk <= 256).
__global__ __launch_bounds__(256) void scan2_kernel(
    int* __restrict__ blocksums, int* __restrict__ blockoffs, int nblk)
{
    __shared__ int sh[256];
    int t = threadIdx.x;
    int v = (t < nblk) ? blocksums[t] : 0;
    sh[t] = v;
    __syncthreads();
    int inc = v;
    #pragma unroll
    for (int ofs = 1; ofs < 256; ofs <<= 1) {
        int add = (t >= ofs) ? sh[t - ofs] : 0;
        __syncthreads();
        inc += add;
        sh[t] = inc;
        __syncthreads();
    }
    if (t < nblk) blockoffs[t] = inc - v;
}

// Add block offsets; also init cursor copy and offsets[N]=E.
__global__ __launch_bounds__(256) void scan3_kernel(
    int* __restrict__ offsets, const int* __restrict__ blockoffs,
    int* __restrict__ cursor, int N, int E)
{
    int i = blockIdx.x * 256 + threadIdx.x;
    if (i < N) {
        int off = offsets[i] + blockoffs[i >> 8];
        offsets[i] = off;
        cursor[i] = off;
    }
    if (i == 0) offsets[N] = E;
}

__global__ __launch_bounds__(256) void position_kernel(
    const int* __restrict__ ei, const int* __restrict__ flag_p,
    int* __restrict__ cursor, int* __restrict__ csr_src, int E)
{
    int e = blockIdx.x * 256 + threadIdx.x;
    if (e >= E) return;
    int is64 = *flag_p;
    int s, d;
    load_edge(ei, is64, E, e, s, d);
    int pos = atomicAdd(&cursor[d], 1);
    csr_src[pos] = s;
}

// ---------- gather-sum: one wave (64 lanes) per node, float2 per lane ----------
__global__ __launch_bounds__(256) void gather_kernel(
    const float* __restrict__ x, const int* __restrict__ offsets,
    const int* __restrict__ csr_src, float* __restrict__ agg, int N)
{
    int node = blockIdx.x * 4 + (threadIdx.x >> 6);
    if (node >= N) return;
    int lane = threadIdx.x & 63;
    int start = offsets[node];
    int deg = offsets[node + 1] - start;

    // prefetch up to 64 src indices into lanes, broadcast via shfl
    int sv = (lane < deg) ? csr_src[start + lane] : 0;

    const float2* x2 = reinterpret_cast<const float2*>(x);
    float2 acc = make_float2(0.0f, 0.0f);
    int dmain = (deg < 64) ? deg : 64;
    for (int i = 0; i < dmain; ++i) {
        int s = __shfl(sv, i);
        float2 v = x2[(size_t)s * 64 + lane];
        acc.x += v.x; acc.y += v.y;
    }
    for (int i = 64; i < deg; ++i) {   // rare tail (deg>64)
        int s = csr_src[start + i];
        float2 v = x2[(size_t)s * 64 + lane];
        acc.x += v.x; acc.y += v.y;
    }
    reinterpret_cast<float2*>(agg)[(size_t)node * 64 + lane] = acc;
}

// ---------- fallback atomic scatter (if ws too small) ----------
__global__ __launch_bounds__(256) void scatter_kernel(
    const float* __restrict__ x, const int* __restrict__ ei,
    const int* __restrict__ flag_p, float* __restrict__ agg, int E)
{
    int tid = blockIdx.x * 256 + threadIdx.x;
    int e = tid >> 5;
    if (e >= E) return;
    int c = (tid & 31) << 2;
    int is64 = *flag_p;
    int s, d;
    load_edge(ei, is64, E, e, s, d);
    float4 v = *reinterpret_cast<const float4*>(x + (size_t)s * F + c);
    float* o = agg + (size_t)d * F + c;
    unsafeAtomicAdd(o + 0, v.x);
    unsafeAtomicAdd(o + 1, v.y);
    unsafeAtomicAdd(o + 2, v.z);
    unsafeAtomicAdd(o + 3, v.w);
}

// ---------- in-place GEMM: io = io @ W + bias ----------
__global__ __launch_bounds__(256) void gemm_kernel(
    float* __restrict__ io, const float* __restrict__ W,
    const float* __restrict__ bias, int N)
{
    __shared__ float sA[TR * LDA];
    __shared__ float sW[KC * F];
    const int t = threadIdx.x;
    const int row0 = blockIdx.x * TR;
    const int g = t & 7;
    const int r = t >> 3;

    float acc[4][16];
    #pragma unroll
    for (int i = 0; i < 4; ++i)
        #pragma unroll
        for (int j = 0; j < 16; ++j) acc[i][j] = 0.0f;

    for (int kc = 0; kc < F; kc += KC) {
        #pragma unroll
        for (int u = 0; u < (TR * KC) / 256; ++u) {
            int idx = u * 256 + t;
            int row = idx >> 5;
            int kk = idx & (KC - 1);
            int grow = row0 + row;
            sA[row * LDA + kk] = (grow < N) ? io[(size_t)grow * F + kc + kk] : 0.0f;
        }
        const float4* Wg = reinterpret_cast<const float4*>(W + (size_t)kc * F);
        float4* sW4 = reinterpret_cast<float4*>(sW);
        #pragma unroll
        for (int u = 0; u < (KC * F / 4) / 256; ++u)
            sW4[u * 256 + t] = Wg[u * 256 + t];
        __syncthreads();

        #pragma unroll 4
        for (int kk = 0; kk < KC; ++kk) {
            const float4 w0 = *reinterpret_cast<const float4*>(&sW[kk * F + g * 16 + 0]);
            const float4 w1 = *reinterpret_cast<const float4*>(&sW[kk * F + g * 16 + 4]);
            const float4 w2 = *reinterpret_cast<const float4*>(&sW[kk * F + g * 16 + 8]);
            const float4 w3 = *reinterpret_cast<const float4*>(&sW[kk * F + g * 16 + 12]);
            #pragma unroll
            for (int i = 0; i < 4; ++i) {
                const float xv = sA[(r * 4 + i) * LDA + kk];
                acc[i][0]  += xv * w0.x;  acc[i][1]  += xv * w0.y;
                acc[i][2]  += xv * w0.z;  acc[i][3]  += xv * w0.w;
                acc[i][4]  += xv * w1.x;  acc[i][5]  += xv * w1.y;
                acc[i][6]  += xv * w1.z;  acc[i][7]  += xv * w1.w;
                acc[i][8]  += xv * w2.x;  acc[i][9]  += xv * w2.y;
                acc[i][10] += xv * w2.z;  acc[i][11] += xv * w2.w;
                acc[i][12] += xv * w3.x;  acc[i][13] += xv * w3.y;
                acc[i][14] += xv * w3.z;  acc[i][15] += xv * w3.w;
            }
        }
        __syncthreads();
    }

    float bv[16];
    #pragma unroll
    for (int j = 0; j < 16; ++j) bv[j] = bias[g * 16 + j];
    #pragma unroll
    for (int i = 0; i < 4; ++i) {
        int row = row0 + r * 4 + i;
        if (row < N) {
            float* o = io + (size_t)row * F + g * 16;
            #pragma unroll
            for (int j4 = 0; j4 < 4; ++j4) {
                float4 v;
                v.x = acc[i][j4 * 4 + 0] + bv[j4 * 4 + 0];
                v.y = acc[i][j4 * 4 + 1] + bv[j4 * 4 + 1];
                v.z = acc[i][j4 * 4 + 2] + bv[j4 * 4 + 2];
                v.w = acc[i][j4 * 4 + 3] + bv[j4 * 4 + 3];
                *reinterpret_cast<float4*>(o + j4 * 4) = v;
            }
        }
    }
}

extern "C" void kernel_launch(void* const* d_in, const int* in_sizes, int n_in,
                              void* d_out, int out_size, void* d_ws, size_t ws_size,
                              hipStream_t stream) {
    const float* x  = (const float*)d_in[0];
    const int*   ei = (const int*)d_in[1];
    const float* W2 = (const float*)d_in[5];
    const float* b2 = (const float*)d_in[6];
    float* out = (float*)d_out;

    const int N = in_sizes[0] / F;   // 50000
    const int E = in_sizes[2];       // 600000
    const int nblk = (N + 255) / 256;

    // workspace layout (ints)
    int* ws = (int*)d_ws;
    int* flag      = ws;                  // [16] (padded)
    int* counts    = flag + 16;           // [N]
    int* offsets   = counts + N;          // [N+1]
    int* cursor    = offsets + N + 1;     // [N]
    int* blocksums = cursor + N;          // [nblk]
    int* blockoffs = blocksums + nblk;    // [nblk]
    int* csr_src   = blockoffs + nblk;    // [E]
    size_t need = (size_t)(16 + 3 * N + 1 + 2 * nblk + E) * sizeof(int);

    detect_kernel<<<1, 64, 0, stream>>>(ei, flag);

    if (ws_size >= need) {
        // CSR path: no feature atomics.
        hipMemsetAsync(counts, 0, (size_t)N * sizeof(int), stream);
        int eblk = (E + 255) / 256;
        hist_kernel<<<eblk, 256, 0, stream>>>(ei, flag, counts, E);
        scan1_kernel<<<nblk, 256, 0, stream>>>(counts, offsets, blocksums, N);
        scan2_kernel<<<1, 256, 0, stream>>>(blocksums, blockoffs, nblk);
        scan3_kernel<<<nblk, 256, 0, stream>>>(offsets, blockoffs, cursor, N, E);
        position_kernel<<<eblk, 256, 0, stream>>>(ei, flag, cursor, csr_src, E);
        gather_kernel<<<(N + 3) / 4, 256, 0, stream>>>(x, offsets, csr_src, out, N);
    } else {
        // fallback: atomic scatter
        hipMemsetAsync(out, 0, (size_t)N * F * sizeof(float), stream);
        int sblocks = (E * 32 + 255) / 256;
        scatter_kernel<<<sblocks, 256, 0, stream>>>(x, ei, flag, out, E);
    }

    gemm_kernel<<<(N + TR - 1) / TR, 256, 0, stream>>>(out, W2, b2, N);
}

// Round 3
// 232.433 us; speedup vs baseline: 4.9391x; 1.0900x over previous
//
#include <hip/hip_runtime.h>

#define F 128
#define TR 64    // GEMM row tile (782 blocks -> ~3/CU)
#define KC 32    // GEMM k chunk
#define LDA 36   // sA leading dim: float4-aligned, 2-way read aliasing (free)
#define LDW 160  // sW row: 8 chunks x 20 floats (distinct banks per g)

// ---------- init: zero counts + dtype detect (int64 vs int32) ----------
__global__ __launch_bounds__(256) void init_kernel(
    const int* __restrict__ ei, int* __restrict__ flag,
    int* __restrict__ counts, int N)
{
    int i = blockIdx.x * 256 + threadIdx.x;
    if (i < N) counts[i] = 0;
    if (i == 0) {
        int or_hi = ei[1] | ei[3] | ei[5] | ei[7] | ei[9] | ei[11] | ei[13] | ei[15];
        *flag = (or_hi == 0) ? 1 : 0;
    }
}

__device__ __forceinline__ void load_edge(const int* ei, int is64, int E, int e,
                                          int& s, int& d)
{
    if (is64) {
        s = ei[2 * (size_t)e];
        d = ei[2 * ((size_t)E + e)];
    } else {
        s = ei[e];
        d = ei[E + e];
    }
}

// ---------- CSR build ----------
__global__ __launch_bounds__(256) void hist_kernel(
    const int* __restrict__ ei, const int* __restrict__ flag_p,
    int* __restrict__ counts, int E)
{
    int e = blockIdx.x * 256 + threadIdx.x;
    if (e >= E) return;
    int is64 = *flag_p;
    int s, d;
    load_edge(ei, is64, E, e, s, d);
    atomicAdd(&counts[d], 1);
}

__global__ __launch_bounds__(256) void scan1_kernel(
    const int* __restrict__ counts, int* __restrict__ offsets,
    int* __restrict__ blocksums, int N)
{
    __shared__ int sh[256];
    int t = threadIdx.x;
    int i = blockIdx.x * 256 + t;
    int v = (i < N) ? counts[i] : 0;
    sh[t] = v;
    __syncthreads();
    int inc = v;
    #pragma unroll
    for (int ofs = 1; ofs < 256; ofs <<= 1) {
        int add = (t >= ofs) ? sh[t - ofs] : 0;
        __syncthreads();
        inc += add;
        sh[t] = inc;
        __syncthreads();
    }
    if (i < N) offsets[i] = inc - v;
    if (t == 255) blocksums[blockIdx.x] = inc;
}

__global__ __launch_bounds__(256) void scan2_kernel(
    int* __restrict__ blocksums, int* __restrict__ blockoffs, int nblk)
{
    __shared__ int sh[256];
    int t = threadIdx.x;
    int v = (t < nblk) ? blocksums[t] : 0;
    sh[t] = v;
    __syncthreads();
    int inc = v;
    #pragma unroll
    for (int ofs = 1; ofs < 256; ofs <<= 1) {
        int add = (t >= ofs) ? sh[t - ofs] : 0;
        __syncthreads();
        inc += add;
        sh[t] = inc;
        __syncthreads();
    }
    if (t < nblk) blockoffs[t] = inc - v;
}

__global__ __launch_bounds__(256) void scan3_kernel(
    int* __restrict__ offsets, const int* __restrict__ blockoffs,
    int* __restrict__ cursor, int N, int E)
{
    int i = blockIdx.x * 256 + threadIdx.x;
    if (i < N) {
        int off = offsets[i] + blockoffs[i >> 8];
        offsets[i] = off;
        cursor[i] = off;
    }
    if (i == 0) offsets[N] = E;
}

__global__ __launch_bounds__(256) void position_kernel(
    const int* __restrict__ ei, const int* __restrict__ flag_p,
    int* __restrict__ cursor, int* __restrict__ csr_src, int E)
{
    int e = blockIdx.x * 256 + threadIdx.x;
    if (e >= E) return;
    int is64 = *flag_p;
    int s, d;
    load_edge(ei, is64, E, e, s, d);
    int pos = atomicAdd(&cursor[d], 1);
    csr_src[pos] = s;
}

// ---------- gather-sum: one wave per node, float2/lane, dual accumulators ----
__global__ __launch_bounds__(256) void gather_kernel(
    const float* __restrict__ x, const int* __restrict__ offsets,
    const int* __restrict__ csr_src, float* __restrict__ agg, int N)
{
    int node = blockIdx.x * 4 + (threadIdx.x >> 6);
    if (node >= N) return;
    int lane = threadIdx.x & 63;
    int start = offsets[node];
    int deg = offsets[node + 1] - start;

    int sv = (lane < deg) ? csr_src[start + lane] : 0;

    const float2* x2 = reinterpret_cast<const float2*>(x);
    float2 a0 = make_float2(0.0f, 0.0f);
    float2 a1 = make_float2(0.0f, 0.0f);
    int dmain = (deg < 64) ? deg : 64;
    int i = 0;
    for (; i + 1 < dmain; i += 2) {
        int s0 = __shfl(sv, i);
        int s1 = __shfl(sv, i + 1);
        float2 v0 = x2[(size_t)s0 * 64 + lane];
        float2 v1 = x2[(size_t)s1 * 64 + lane];
        a0.x += v0.x; a0.y += v0.y;
        a1.x += v1.x; a1.y += v1.y;
    }
    if (i < dmain) {
        int s = __shfl(sv, i);
        float2 v = x2[(size_t)s * 64 + lane];
        a0.x += v.x; a0.y += v.y;
    }
    for (int j = 64; j < deg; ++j) {   // rare tail (deg > 64)
        int s = csr_src[start + j];
        float2 v = x2[(size_t)s * 64 + lane];
        a0.x += v.x; a0.y += v.y;
    }
    a0.x += a1.x; a0.y += a1.y;
    reinterpret_cast<float2*>(agg)[(size_t)node * 64 + lane] = a0;
}

// ---------- fallback atomic scatter (if ws too small) ----------
__global__ __launch_bounds__(256) void scatter_kernel(
    const float* __restrict__ x, const int* __restrict__ ei,
    const int* __restrict__ flag_p, float* __restrict__ agg, int E)
{
    int tid = blockIdx.x * 256 + threadIdx.x;
    int e = tid >> 5;
    if (e >= E) return;
    int c = (tid & 31) << 2;
    int is64 = *flag_p;
    int s, d;
    load_edge(ei, is64, E, e, s, d);
    float4 v = *reinterpret_cast<const float4*>(x + (size_t)s * F + c);
    float* o = agg + (size_t)d * F + c;
    unsafeAtomicAdd(o + 0, v.x);
    unsafeAtomicAdd(o + 1, v.y);
    unsafeAtomicAdd(o + 2, v.z);
    unsafeAtomicAdd(o + 3, v.w);
}

// ---------- in-place GEMM: io = io @ W + bias ----------
// TR=64 rows/block; 256 threads; thread = (g: 16 cols, r: 2 rows).
// sW stored in 20-float-padded 16-col chunks: g*20 % 32 all-distinct banks.
__global__ __launch_bounds__(256) void gemm_kernel(
    float* __restrict__ io, const float* __restrict__ W,
    const float* __restrict__ bias, int N)
{
    __shared__ float sA[TR * LDA];   // 64*36*4  = 9216 B
    __shared__ float sW[KC * LDW];   // 32*160*4 = 20480 B
    const int t = threadIdx.x;
    const int row0 = blockIdx.x * TR;
    const int g = t & 7;             // cols g*16 .. g*16+15
    const int r = t >> 3;            // rows r*2, r*2+1 (r in 0..31)

    float acc[2][16];
    #pragma unroll
    for (int i = 0; i < 2; ++i)
        #pragma unroll
        for (int j = 0; j < 16; ++j) acc[i][j] = 0.0f;

    for (int kc = 0; kc < F; kc += KC) {
        // stage A: 64 rows x 32 k = 512 float4, 2 per thread
        #pragma unroll
        for (int u = 0; u < 2; ++u) {
            int idx = u * 256 + t;
            int row = idx >> 3;
            int k4 = (idx & 7) * 4;
            int grow = row0 + row;
            float4 v = (grow < N)
                ? *reinterpret_cast<const float4*>(io + (size_t)grow * F + kc + k4)
                : make_float4(0.f, 0.f, 0.f, 0.f);
            *reinterpret_cast<float4*>(&sA[row * LDA + k4]) = v;
        }
        // stage W: 32 k-rows x 128 f = 1024 float4, 4 per thread, chunked layout
        #pragma unroll
        for (int u = 0; u < 4; ++u) {
            int idx = u * 256 + t;
            int kk = idx >> 5;
            int f4 = (idx & 31) * 4;
            float4 v = *reinterpret_cast<const float4*>(W + (size_t)(kc + kk) * F + f4);
            int chunk = f4 >> 4;
            int within = f4 & 15;
            *reinterpret_cast<float4*>(&sW[kk * LDW + chunk * 20 + within]) = v;
        }
        __syncthreads();

        #pragma unroll 8
        for (int kk = 0; kk < KC; ++kk) {
            const float* wp = &sW[kk * LDW + g * 20];
            const float4 w0 = *reinterpret_cast<const float4*>(wp + 0);
            const float4 w1 = *reinterpret_cast<const float4*>(wp + 4);
            const float4 w2 = *reinterpret_cast<const float4*>(wp + 8);
            const float4 w3 = *reinterpret_cast<const float4*>(wp + 12);
            #pragma unroll
            for (int i = 0; i < 2; ++i) {
                const float xv = sA[(r * 2 + i) * LDA + kk];
                acc[i][0]  += xv * w0.x;  acc[i][1]  += xv * w0.y;
                acc[i][2]  += xv * w0.z;  acc[i][3]  += xv * w0.w;
                acc[i][4]  += xv * w1.x;  acc[i][5]  += xv * w1.y;
                acc[i][6]  += xv * w1.z;  acc[i][7]  += xv * w1.w;
                acc[i][8]  += xv * w2.x;  acc[i][9]  += xv * w2.y;
                acc[i][10] += xv * w2.z;  acc[i][11] += xv * w2.w;
                acc[i][12] += xv * w3.x;  acc[i][13] += xv * w3.y;
                acc[i][14] += xv * w3.z;  acc[i][15] += xv * w3.w;
            }
        }
        __syncthreads();
    }

    float bv[16];
    #pragma unroll
    for (int j = 0; j < 16; ++j) bv[j] = bias[g * 16 + j];
    #pragma unroll
    for (int i = 0; i < 2; ++i) {
        int row = row0 + r * 2 + i;
        if (row < N) {
            float* o = io + (size_t)row * F + g * 16;
            #pragma unroll
            for (int j4 = 0; j4 < 4; ++j4) {
                float4 v;
                v.x = acc[i][j4 * 4 + 0] + bv[j4 * 4 + 0];
                v.y = acc[i][j4 * 4 + 1] + bv[j4 * 4 + 1];
                v.z = acc[i][j4 * 4 + 2] + bv[j4 * 4 + 2];
                v.w = acc[i][j4 * 4 + 3] + bv[j4 * 4 + 3];
                *reinterpret_cast<float4*>(o + j4 * 4) = v;
            }
        }
    }
}

extern "C" void kernel_launch(void* const* d_in, const int* in_sizes, int n_in,
                              void* d_out, int out_size, void* d_ws, size_t ws_size,
                              hipStream_t stream) {
    const float* x  = (const float*)d_in[0];
    const int*   ei = (const int*)d_in[1];
    const float* W2 = (const float*)d_in[5];
    const float* b2 = (const float*)d_in[6];
    float* out = (float*)d_out;

    const int N = in_sizes[0] / F;   // 50000
    const int E = in_sizes[2];       // 600000
    const int nblk = (N + 255) / 256;

    int* ws = (int*)d_ws;
    int* flag      = ws;                  // [16]
    int* counts    = flag + 16;           // [N]
    int* offsets   = counts + N;          // [N+1]
    int* cursor    = offsets + N + 1;     // [N]
    int* blocksums = cursor + N;          // [nblk]
    int* blockoffs = blocksums + nblk;    // [nblk]
    int* csr_src   = blockoffs + nblk;    // [E]
    size_t need = (size_t)(16 + 3 * N + 1 + 2 * nblk + E) * sizeof(int);

    if (ws_size >= need) {
        init_kernel<<<nblk, 256, 0, stream>>>(ei, flag, counts, N);
        int eblk = (E + 255) / 256;
        hist_kernel<<<eblk, 256, 0, stream>>>(ei, flag, counts, E);
        scan1_kernel<<<nblk, 256, 0, stream>>>(counts, offsets, blocksums, N);
        scan2_kernel<<<1, 256, 0, stream>>>(blocksums, blockoffs, nblk);
        scan3_kernel<<<nblk, 256, 0, stream>>>(offsets, blockoffs, cursor, N, E);
        position_kernel<<<eblk, 256, 0, stream>>>(ei, flag, cursor, csr_src, E);
        gather_kernel<<<(N + 3) / 4, 256, 0, stream>>>(x, offsets, csr_src, out, N);
    } else {
        init_kernel<<<1, 64, 0, stream>>>(ei, flag, (int*)d_ws + 16, 0);
        hipMemsetAsync(out, 0, (size_t)N * F * sizeof(float), stream);
        int sblocks = (E * 32 + 255) / 256;
        scatter_kernel<<<sblocks, 256, 0, stream>>>(x, ei, flag, out, E);
    }

    gemm_kernel<<<(N + TR - 1) / TR, 256, 0, stream>>>(out, W2, b2, N);
}

// Round 4
// 226.733 us; speedup vs baseline: 5.0633x; 1.0251x over previous
//
#include <hip/hip_runtime.h>

#define F 128
#define TR 64    // GEMM row tile
#define KC 32    // GEMM k chunk
#define LDA 36   // sA leading dim: float4-aligned, 2-way read aliasing (free)
#define LDW 160  // sW row: 8 chunks x 20 floats (distinct banks per g)

// ---------- init: zero counts + dtype detect (int64 vs int32) ----------
__global__ __launch_bounds__(256) void init_kernel(
    const int* __restrict__ ei, int* __restrict__ flag,
    int* __restrict__ counts, int N)
{
    int i = blockIdx.x * 256 + threadIdx.x;
    if (i < N) counts[i] = 0;
    if (i == 0) {
        int or_hi = ei[1] | ei[3] | ei[5] | ei[7] | ei[9] | ei[11] | ei[13] | ei[15];
        *flag = (or_hi == 0) ? 1 : 0;
    }
}

// ---------- CSR build ----------
__global__ __launch_bounds__(256) void hist_kernel(
    const int* __restrict__ ei, const int* __restrict__ flag_p,
    int* __restrict__ counts, int E)
{
    int e = blockIdx.x * 256 + threadIdx.x;
    if (e >= E) return;
    int d;
    if (*flag_p) d = reinterpret_cast<const int2*>(ei)[(size_t)E + e].x;
    else         d = ei[E + e];
    atomicAdd(&counts[d], 1);
}

// Block-local exclusive scan; writes locoff + cursor copy + blocksums.
__global__ __launch_bounds__(256) void scan1_kernel(
    const int* __restrict__ counts, int* __restrict__ locoff,
    int* __restrict__ cursor, int* __restrict__ blocksums, int N)
{
    __shared__ int sh[256];
    int t = threadIdx.x;
    int i = blockIdx.x * 256 + t;
    int v = (i < N) ? counts[i] : 0;
    sh[t] = v;
    __syncthreads();
    int inc = v;
    #pragma unroll
    for (int ofs = 1; ofs < 256; ofs <<= 1) {
        int add = (t >= ofs) ? sh[t - ofs] : 0;
        __syncthreads();
        inc += add;
        sh[t] = inc;
        __syncthreads();
    }
    if (i < N) { locoff[i] = inc - v; cursor[i] = inc - v; }
    if (t == 255) blocksums[blockIdx.x] = inc;
}

// Single block: exclusive scan of blocksums (nblk <= 256).
__global__ __launch_bounds__(256) void scan2_kernel(
    int* __restrict__ blocksums, int* __restrict__ blockoffs, int nblk)
{
    __shared__ int sh[256];
    int t = threadIdx.x;
    int v = (t < nblk) ? blocksums[t] : 0;
    sh[t] = v;
    __syncthreads();
    int inc = v;
    #pragma unroll
    for (int ofs = 1; ofs < 256; ofs <<= 1) {
        int add = (t >= ofs) ? sh[t - ofs] : 0;
        __syncthreads();
        inc += add;
        sh[t] = inc;
        __syncthreads();
    }
    if (t < nblk) blockoffs[t] = inc - v;
}

__global__ __launch_bounds__(256) void position_kernel(
    const int* __restrict__ ei, const int* __restrict__ flag_p,
    int* __restrict__ cursor, const int* __restrict__ blockoffs,
    int* __restrict__ csr_src, int E)
{
    int e = blockIdx.x * 256 + threadIdx.x;
    if (e >= E) return;
    int s, d;
    if (*flag_p) {
        s = reinterpret_cast<const int2*>(ei)[e].x;
        d = reinterpret_cast<const int2*>(ei)[(size_t)E + e].x;
    } else {
        s = ei[e];
        d = ei[E + e];
    }
    int pos = atomicAdd(&cursor[d], 1) + blockoffs[d >> 8];
    csr_src[pos] = s;
}

// ---------- gather-sum: one node per wave; 2 half-waves process 2 edges ----
// Each lane loads a full float4 (16B); 4 edges (2x unroll) in flight.
__global__ __launch_bounds__(256) void gather_kernel(
    const float* __restrict__ x, const int* __restrict__ locoff,
    const int* __restrict__ blockoffs, const int* __restrict__ counts,
    const int* __restrict__ csr_src, float* __restrict__ agg, int N)
{
    int node = blockIdx.x * 4 + (threadIdx.x >> 6);
    if (node >= N) return;
    int lane = threadIdx.x & 63;
    int half = lane >> 5;        // which edge of the pair
    int col = lane & 31;         // float4 column within the row
    int start = locoff[node] + blockoffs[node >> 8];
    int deg = counts[node];

    const float4* x4 = reinterpret_cast<const float4*>(x);
    float4 a0 = make_float4(0.f, 0.f, 0.f, 0.f);
    float4 a1 = make_float4(0.f, 0.f, 0.f, 0.f);

    for (int base = 0; base < deg; base += 64) {
        int rem = deg - base; if (rem > 64) rem = 64;
        int sv = (lane < rem) ? csr_src[start + base + lane] : 0;
        int i = 0;
        for (; i + 3 < rem; i += 4) {          // 4 edges per iteration
            int e0 = __shfl(sv, i + half);
            int e1 = __shfl(sv, i + 2 + half);
            float4 v0 = x4[(size_t)e0 * 32 + col];
            float4 v1 = x4[(size_t)e1 * 32 + col];
            a0.x += v0.x; a0.y += v0.y; a0.z += v0.z; a0.w += v0.w;
            a1.x += v1.x; a1.y += v1.y; a1.z += v1.z; a1.w += v1.w;
        }
        for (; i + 1 < rem; i += 2) {          // 2 edges
            int e0 = __shfl(sv, i + half);
            float4 v0 = x4[(size_t)e0 * 32 + col];
            a0.x += v0.x; a0.y += v0.y; a0.z += v0.z; a0.w += v0.w;
        }
        if (i < rem) {                          // final odd edge: half 0 only
            int e0 = __shfl(sv, i);
            if (half == 0) {
                float4 v = x4[(size_t)e0 * 32 + col];
                a0.x += v.x; a0.y += v.y; a0.z += v.z; a0.w += v.w;
            }
        }
    }
    a0.x += a1.x; a0.y += a1.y; a0.z += a1.z; a0.w += a1.w;
    // combine the two half-wave partial sums
    a0.x += __shfl_xor(a0.x, 32);
    a0.y += __shfl_xor(a0.y, 32);
    a0.z += __shfl_xor(a0.z, 32);
    a0.w += __shfl_xor(a0.w, 32);
    if (half == 0)
        reinterpret_cast<float4*>(agg)[(size_t)node * 32 + col] = a0;
}

// ---------- fallback atomic scatter (if ws too small) ----------
__global__ __launch_bounds__(256) void scatter_kernel(
    const float* __restrict__ x, const int* __restrict__ ei,
    const int* __restrict__ flag_p, float* __restrict__ agg, int E)
{
    int tid = blockIdx.x * 256 + threadIdx.x;
    int e = tid >> 5;
    if (e >= E) return;
    int c = (tid & 31) << 2;
    int s, d;
    if (*flag_p) {
        s = reinterpret_cast<const int2*>(ei)[e].x;
        d = reinterpret_cast<const int2*>(ei)[(size_t)E + e].x;
    } else {
        s = ei[e];
        d = ei[E + e];
    }
    float4 v = *reinterpret_cast<const float4*>(x + (size_t)s * F + c);
    float* o = agg + (size_t)d * F + c;
    unsafeAtomicAdd(o + 0, v.x);
    unsafeAtomicAdd(o + 1, v.y);
    unsafeAtomicAdd(o + 2, v.z);
    unsafeAtomicAdd(o + 3, v.w);
}

// ---------- in-place GEMM: io = io @ W + bias ----------
__global__ __launch_bounds__(256) void gemm_kernel(
    float* __restrict__ io, const float* __restrict__ W,
    const float* __restrict__ bias, int N)
{
    __shared__ float sA[TR * LDA];
    __shared__ float sW[KC * LDW];
    const int t = threadIdx.x;
    const int row0 = blockIdx.x * TR;
    const int g = t & 7;
    const int r = t >> 3;

    float acc[2][16];
    #pragma unroll
    for (int i = 0; i < 2; ++i)
        #pragma unroll
        for (int j = 0; j < 16; ++j) acc[i][j] = 0.0f;

    for (int kc = 0; kc < F; kc += KC) {
        #pragma unroll
        for (int u = 0; u < 2; ++u) {
            int idx = u * 256 + t;
            int row = idx >> 3;
            int k4 = (idx & 7) * 4;
            int grow = row0 + row;
            float4 v = (grow < N)
                ? *reinterpret_cast<const float4*>(io + (size_t)grow * F + kc + k4)
                : make_float4(0.f, 0.f, 0.f, 0.f);
            *reinterpret_cast<float4*>(&sA[row * LDA + k4]) = v;
        }
        #pragma unroll
        for (int u = 0; u < 4; ++u) {
            int idx = u * 256 + t;
            int kk = idx >> 5;
            int f4 = (idx & 31) * 4;
            float4 v = *reinterpret_cast<const float4*>(W + (size_t)(kc + kk) * F + f4);
            int chunk = f4 >> 4;
            int within = f4 & 15;
            *reinterpret_cast<float4*>(&sW[kk * LDW + chunk * 20 + within]) = v;
        }
        __syncthreads();

        #pragma unroll 8
        for (int kk = 0; kk < KC; ++kk) {
            const float* wp = &sW[kk * LDW + g * 20];
            const float4 w0 = *reinterpret_cast<const float4*>(wp + 0);
            const float4 w1 = *reinterpret_cast<const float4*>(wp + 4);
            const float4 w2 = *reinterpret_cast<const float4*>(wp + 8);
            const float4 w3 = *reinterpret_cast<const float4*>(wp + 12);
            #pragma unroll
            for (int i = 0; i < 2; ++i) {
                const float xv = sA[(r * 2 + i) * LDA + kk];
                acc[i][0]  += xv * w0.x;  acc[i][1]  += xv * w0.y;
                acc[i][2]  += xv * w0.z;  acc[i][3]  += xv * w0.w;
                acc[i][4]  += xv * w1.x;  acc[i][5]  += xv * w1.y;
                acc[i][6]  += xv * w1.z;  acc[i][7]  += xv * w1.w;
                acc[i][8]  += xv * w2.x;  acc[i][9]  += xv * w2.y;
                acc[i][10] += xv * w2.z;  acc[i][11] += xv * w2.w;
                acc[i][12] += xv * w3.x;  acc[i][13] += xv * w3.y;
                acc[i][14] += xv * w3.z;  acc[i][15] += xv * w3.w;
            }
        }
        __syncthreads();
    }

    float bv[16];
    #pragma unroll
    for (int j = 0; j < 16; ++j) bv[j] = bias[g * 16 + j];
    #pragma unroll
    for (int i = 0; i < 2; ++i) {
        int row = row0 + r * 2 + i;
        if (row < N) {
            float* o = io + (size_t)row * F + g * 16;
            #pragma unroll
            for (int j4 = 0; j4 < 4; ++j4) {
                float4 v;
                v.x = acc[i][j4 * 4 + 0] + bv[j4 * 4 + 0];
                v.y = acc[i][j4 * 4 + 1] + bv[j4 * 4 + 1];
                v.z = acc[i][j4 * 4 + 2] + bv[j4 * 4 + 2];
                v.w = acc[i][j4 * 4 + 3] + bv[j4 * 4 + 3];
                *reinterpret_cast<float4*>(o + j4 * 4) = v;
            }
        }
    }
}

extern "C" void kernel_launch(void* const* d_in, const int* in_sizes, int n_in,
                              void* d_out, int out_size, void* d_ws, size_t ws_size,
                              hipStream_t stream) {
    const float* x  = (const float*)d_in[0];
    const int*   ei = (const int*)d_in[1];
    const float* W2 = (const float*)d_in[5];
    const float* b2 = (const float*)d_in[6];
    float* out = (float*)d_out;

    const int N = in_sizes[0] / F;   // 50000
    const int E = in_sizes[2];       // 600000
    const int nblk = (N + 255) / 256;

    int* ws = (int*)d_ws;
    int* flag      = ws;                  // [16]
    int* counts    = flag + 16;           // [N]
    int* locoff    = counts + N;          // [N]
    int* cursor    = locoff + N;          // [N]
    int* blocksums = cursor + N;          // [nblk]
    int* blockoffs = blocksums + nblk;    // [nblk]
    int* csr_src   = blockoffs + nblk;    // [E]
    size_t need = (size_t)(16 + 3 * N + 2 * nblk + E) * sizeof(int);

    if (ws_size >= need) {
        init_kernel<<<nblk, 256, 0, stream>>>(ei, flag, counts, N);
        int eblk = (E + 255) / 256;
        hist_kernel<<<eblk, 256, 0, stream>>>(ei, flag, counts, E);
        scan1_kernel<<<nblk, 256, 0, stream>>>(counts, locoff, cursor, blocksums, N);
        scan2_kernel<<<1, 256, 0, stream>>>(blocksums, blockoffs, nblk);
        position_kernel<<<eblk, 256, 0, stream>>>(ei, flag, cursor, blockoffs, csr_src, E);
        gather_kernel<<<(N + 3) / 4, 256, 0, stream>>>(x, locoff, blockoffs, counts,
                                                       csr_src, out, N);
    } else {
        init_kernel<<<1, 64, 0, stream>>>(ei, flag, (int*)d_ws + 16, 0);
        hipMemsetAsync(out, 0, (size_t)N * F * sizeof(float), stream);
        int sblocks = (E * 32 + 255) / 256;
        scatter_kernel<<<sblocks, 256, 0, stream>>>(x, ei, flag, out, E);
    }

    gemm_kernel<<<(N + TR - 1) / TR, 256, 0, stream>>>(out, W2, b2, N);
}